// Round 1
// baseline (2587.430 us; speedup 1.0000x reference)
//
#include <hip/hip_runtime.h>
#include <hip/hip_bf16.h>
#include <hip/hip_fp16.h>

typedef short bf16x8 __attribute__((ext_vector_type(8)));
typedef float f32x4 __attribute__((ext_vector_type(4)));
typedef _Float16 half2v __attribute__((ext_vector_type(2)));
typedef unsigned int uint32;

#define MFMA_B16(a,b,c) __builtin_amdgcn_mfma_f32_16x16x32_bf16(a,b,c,0,0,0)

// ---------------- geometry ----------------
#define NS   1024   // sentences
#define TLEN 128    // words per sentence
#define DD   343    // input dim
#define HH   150    // hidden per dir
#define GG   600    // 4*HH
#define KX   352    // padded DD (11 k-steps of 32)
#define KXP  44     // KX/8 panels
#define KH   160    // padded HH (5 k-steps)
#define KHP  20
#define NP   640    // padded gate dim (40 n-tiles of 16)

// ---------------- ws layout (bytes) ----------------
#define OFF_WXP  0u          // bf16 [2][44][640][8]   = 901120 B
#define OFF_WHP  901120u     // bf16 [2][20][640][8]   = 409600 B
#define OFF_B1   1310720u    // f32  [2][640]          = 5120 B
#define OFF_W2   1315840u    // f16  [2][600][152]     = 364800 B
#define OFF_W2I  1680640u    // f32  [2][300][608]     = 1459200 B
#define OFF_SE   3139840u    // f32  [1024][300]       = 1228800 B
#define OFF_XG2  4368640u    // f32  [2][1024][600]    = 4915200 B
#define OFF_H2O  9283840u    // f32  [1024][300]       = 1228800 B

// prep section boundaries (element counts)
#define PE0 450560   // WXp elems
#define PE1 655360   // + WHp (204800)
#define PE2 656640   // + B1 (1280)
#define PE3 839040   // + W2 (182400)
#define PE4 1203840  // + W2I (364800)

__device__ __forceinline__ float rcp_fast(float x) { return __builtin_amdgcn_rcpf(x); }
__device__ __forceinline__ float sigm(float x) { return rcp_fast(1.f + __expf(-x)); }
__device__ __forceinline__ float tanh_fast(float x) { return 1.f - 2.f * rcp_fast(__expf(2.f * x) + 1.f); }

__device__ __forceinline__ float fdot2u(uint32 a, uint32 b, float c) {
  half2v av = __builtin_bit_cast(half2v, a);
  half2v bv = __builtin_bit_cast(half2v, b);
  return __builtin_amdgcn_fdot2(av, bv, c, false);
}

// ---------------- prep: pack weights into MFMA-friendly layouts ----------------
__global__ __launch_bounds__(256) void prep_kernel(
    const float* __restrict__ wif1, const float* __restrict__ whf1,
    const float* __restrict__ bif1, const float* __restrict__ bhf1,
    const float* __restrict__ wib1, const float* __restrict__ whb1,
    const float* __restrict__ bib1, const float* __restrict__ bhb1,
    const float* __restrict__ wif2, const float* __restrict__ wib2,
    const float* __restrict__ whf2, const float* __restrict__ whb2,
    __hip_bfloat16* __restrict__ WXp, __hip_bfloat16* __restrict__ WHp,
    float* __restrict__ B1, _Float16* __restrict__ W2, float* __restrict__ W2I)
{
  int i = blockIdx.x * 256 + threadIdx.x;
  if (i < PE0) {
    // WXp[d][p][n][j] = w_ih[n][p*8+j]  (zero padded)
    int d = i / 225280; int r = i - d * 225280;
    int p = r / 5120;   int r2 = r - p * 5120;
    int n = r2 >> 3;    int j = r2 & 7;
    int k = p * 8 + j;
    const float* w = d ? wib1 : wif1;
    float v = (n < GG && k < DD) ? w[n * DD + k] : 0.f;
    WXp[i] = __float2bfloat16(v);
  } else if (i < PE1) {
    int ii = i - PE0;
    int d = ii / 102400; int r = ii - d * 102400;
    int p = r / 5120;    int r2 = r - p * 5120;
    int n = r2 >> 3;     int j = r2 & 7;
    int k = p * 8 + j;
    const float* w = d ? whb1 : whf1;
    float v = (n < GG && k < HH) ? w[n * HH + k] : 0.f;
    WHp[ii] = __float2bfloat16(v);
  } else if (i < PE2) {
    int ii = i - PE1;
    int d = ii / NP; int n = ii - d * NP;
    float v = 0.f;
    if (n < GG) v = d ? (bib1[n] + bhb1[n]) : (bif1[n] + bhf1[n]);
    B1[ii] = v;
  } else if (i < PE3) {
    int ii = i - PE2;
    int d = ii / 91200; int r = ii - d * 91200;
    int n = r / 152;    int k = r - n * 152;
    const float* w = d ? whb2 : whf2;
    float v = (k < HH) ? w[n * HH + k] : 0.f;
    W2[ii] = (_Float16)v;
  } else if (i < PE4) {
    int ii = i - PE3;
    int d = ii / 182400; int r = ii - d * 182400;
    int k = r / 608;     int n = r - k * 608;
    const float* w = d ? wib2 : wif2;
    float v = (n < GG) ? w[n * 300 + k] : 0.f;
    W2I[ii] = v;
  }
}

// ---------------- layer-1: fused input-proj + recurrence + max-pool ----------------
// grid = 128 blocks: (64 sentence groups of 16) x 2 dirs. 512 threads = 8 waves,
// wave w owns gate columns [80w, 80w+80).  Time-batched TB=4: x-projection for 4
// steps is computed once per weight pass and kept in the MFMA accumulators.
#define XS_OFF 0u            // bf16 [4][16][360] = 46080
#define HS_OFF 46080u        // bf16 [16][168]    = 5376
#define GS_OFF 51456u        // f32  [16][601]    = 38464
#define CF_OFF 89920u        // f32  [16][152]    = 9728
#define MX_OFF 99648u        // f32  [16][152]    = 9728
#define BB_OFF 109376u       // f32  [640]        = 2560
#define L1_SMEM 111936u

__global__ __launch_bounds__(512, 2) void lstm1_kernel(
    const float* __restrict__ x, const __hip_bfloat16* __restrict__ WXp,
    const __hip_bfloat16* __restrict__ WHp, const float* __restrict__ B1,
    float* __restrict__ SE)
{
  extern __shared__ char smem[];
  __hip_bfloat16* xs = (__hip_bfloat16*)(smem + XS_OFF);
  __hip_bfloat16* hs = (__hip_bfloat16*)(smem + HS_OFF);
  float* gs = (float*)(smem + GS_OFF);
  float* cf = (float*)(smem + CF_OFF);
  float* mx = (float*)(smem + MX_OFF);
  float* bb = (float*)(smem + BB_OFF);

  const int tid = threadIdx.x;
  const int dir = blockIdx.x & 1;
  const int s0 = (blockIdx.x >> 1) * 16;
  const int lane = tid & 63;
  const int wv = tid >> 6;
  const int nb = wv * 80;
  const int arow = lane & 15;
  const int kgrp = lane >> 4;

  for (int e = tid; e < 16 * 168; e += 512) hs[e] = __float2bfloat16(0.f);
  for (int e = tid; e < 16 * 152; e += 512) { cf[e] = 0.f; mx[e] = -1e30f; }
  for (int e = tid; e < NP; e += 512) bb[e] = B1[dir * NP + e];
  __syncthreads();

  const __hip_bfloat16* WXd = WXp + (size_t)dir * KXP * NP * 8;
  const __hip_bfloat16* WHd = WHp + (size_t)dir * KHP * NP * 8;

  for (int g = 0; g < 32; ++g) {
    const int t0 = g * 4;
    // ---- stage x for 4 steps (bf16, zero-padded cols 343..351) ----
    for (int tb = 0; tb < 4; ++tb) {
      const int tt = dir ? (127 - (t0 + tb)) : (t0 + tb);
      for (int e = tid; e < 16 * KX; e += 512) {
        int i = e / KX, k = e - i * KX;
        float v = (k < DD) ? x[(((size_t)(s0 + i)) * TLEN + tt) * DD + k] : 0.f;
        xs[(tb * 16 + i) * 360 + k] = __float2bfloat16(v);
      }
    }
    __syncthreads();

    f32x4 acc[4][5];
    #pragma unroll
    for (int tb = 0; tb < 4; ++tb)
      #pragma unroll
      for (int nt = 0; nt < 5; ++nt) acc[tb][nt] = (f32x4){0.f, 0.f, 0.f, 0.f};

    // ---- phase A: x-projection for all 4 steps ----
    for (int kk = 0; kk < 11; ++kk) {
      bf16x8 a[4], b[5];
      #pragma unroll
      for (int tb = 0; tb < 4; ++tb)
        a[tb] = *reinterpret_cast<const bf16x8*>(xs + (tb * 16 + arow) * 360 + kk * 32 + kgrp * 8);
      #pragma unroll
      for (int nt = 0; nt < 5; ++nt)
        b[nt] = *reinterpret_cast<const bf16x8*>(WXd + ((size_t)(kk * 4 + kgrp) * NP + nb + nt * 16 + arow) * 8);
      #pragma unroll
      for (int tb = 0; tb < 4; ++tb)
        #pragma unroll
        for (int nt = 0; nt < 5; ++nt)
          acc[tb][nt] = MFMA_B16(a[tb], b[nt], acc[tb][nt]);
    }

    // ---- phase B: 4 sequential recurrent steps ----
    #pragma unroll
    for (int tb = 0; tb < 4; ++tb) {
      #pragma unroll
      for (int kh = 0; kh < 5; ++kh) {
        bf16x8 ah = *reinterpret_cast<const bf16x8*>(hs + arow * 168 + kh * 32 + kgrp * 8);
        #pragma unroll
        for (int nt = 0; nt < 5; ++nt) {
          bf16x8 bh = *reinterpret_cast<const bf16x8*>(WHd + ((size_t)(kh * 4 + kgrp) * NP + nb + nt * 16 + arow) * 8);
          acc[tb][nt] = MFMA_B16(ah, bh, acc[tb][nt]);
        }
      }
      // epilogue: bias + gate nonlinearity -> gs
      #pragma unroll
      for (int nt = 0; nt < 5; ++nt) {
        int n = nb + nt * 16 + arow;
        if (n < GG) {
          float bias = bb[n];
          bool isg = (n >= 300) && (n < 450);
          #pragma unroll
          for (int r = 0; r < 4; ++r) {
            float v = acc[tb][nt][r] + bias;
            gs[(kgrp * 4 + r) * 601 + n] = isg ? tanh_fast(v) : sigm(v);
          }
        }
      }
      __syncthreads();
      // cell/hidden update + running max-pool
      for (int e = tid; e < 16 * HH; e += 512) {
        int s = e / HH, j = e - s * HH;
        float iv = gs[s * 601 + j];
        float fv = gs[s * 601 + 150 + j];
        float gv = gs[s * 601 + 300 + j];
        float ov = gs[s * 601 + 450 + j];
        float c = fv * cf[s * 152 + j] + iv * gv;
        float nh = ov * tanh_fast(c);
        cf[s * 152 + j] = c;
        mx[s * 152 + j] = fmaxf(mx[s * 152 + j], nh);
        hs[s * 168 + j] = __float2bfloat16(nh);
      }
      __syncthreads();
    }
  }

  for (int e = tid; e < 16 * HH; e += 512) {
    int s = e / HH, j = e - s * HH;
    SE[(size_t)(s0 + s) * 300 + dir * HH + j] = mx[s * 152 + j];
  }
}

// ---------------- layer-2 input projection: xg2 = SE @ w_ih2^T + biases ----------------
__global__ __launch_bounds__(256, 1) void xg2_kernel(
    const float* __restrict__ SE, const float* __restrict__ W2I,
    const float* __restrict__ bif2, const float* __restrict__ bhf2,
    const float* __restrict__ bib2, const float* __restrict__ bhb2,
    float* __restrict__ XG2)
{
  __shared__ float se[32 * 304];
  const int d = blockIdx.x >> 5, st = blockIdx.x & 31, sb = st * 32;
  const int tid = threadIdx.x;
  for (int e = tid; e < 32 * 300; e += 256) {
    int si = e / 300, k = e - si * 300;
    se[si * 304 + k] = SE[(size_t)(sb + si) * 300 + k];
  }
  __syncthreads();
  for (int pass = 0; pass < 3; ++pass) {
    int n = pass * 256 + tid;
    if (n < GG) {
      float bias = d ? (bib2[n] + bhb2[n]) : (bif2[n] + bhf2[n]);
      float acc[32];
      #pragma unroll
      for (int si = 0; si < 32; ++si) acc[si] = bias;
      const float* wcol = W2I + (size_t)d * 300 * 608 + n;
      for (int k = 0; k < 300; ++k) {
        float wvv = wcol[(size_t)k * 608];
        #pragma unroll
        for (int si = 0; si < 32; ++si) acc[si] += wvv * se[si * 304 + k];
      }
      #pragma unroll
      for (int si = 0; si < 32; ++si)
        XG2[((size_t)d * NS + sb + si) * GG + n] = acc[si];
    }
  }
}

// ---------------- layer-2 recurrence: 2 blocks (fwd, bwd), w_hh in registers ----------------
__global__ __launch_bounds__(640, 3) void lstm2_kernel(
    const _Float16* __restrict__ W2, const float* __restrict__ XG2,
    float* __restrict__ H2O)
{
  const int dir = blockIdx.x;
  const int t = threadIdx.x;
  __shared__ float gls[GG];
  __shared__ __align__(16) uint32 hp[80];   // h as 152 f16 (76 uints) + pad

  uint32 w2p[76];
  if (t < GG) {
    const uint32* wr = (const uint32*)(W2 + ((size_t)dir * GG + t) * 152);
    #pragma unroll
    for (int q = 0; q < 76; ++q) w2p[q] = wr[q];
  }
  if (t < 80) hp[t] = 0u;
  __syncthreads();

  float creg = 0.f;
  const float* xg = XG2 + (size_t)dir * NS * GG;
  int ss0 = dir ? 1023 : 0;
  float xnext = (t < GG) ? xg[(size_t)ss0 * GG + t] : 0.f;

  for (int step = 0; step < 1024; ++step) {
    const int ss = dir ? (1023 - step) : step;
    float acc = xnext;
    float xn = 0.f;
    if (step < 1023 && t < GG) {
      int ss2 = dir ? (1022 - step) : (step + 1);
      xn = xg[(size_t)ss2 * GG + t];
    }
    if (t < GG) {
      const uint4* hp4 = reinterpret_cast<const uint4*>(hp);
      #pragma unroll
      for (int q4 = 0; q4 < 19; ++q4) {
        uint4 hv = hp4[q4];
        acc = fdot2u(hv.x, w2p[q4 * 4 + 0], acc);
        acc = fdot2u(hv.y, w2p[q4 * 4 + 1], acc);
        acc = fdot2u(hv.z, w2p[q4 * 4 + 2], acc);
        acc = fdot2u(hv.w, w2p[q4 * 4 + 3], acc);
      }
      bool isg = (t >= 300) && (t < 450);
      gls[t] = isg ? tanh_fast(acc) : sigm(acc);
    }
    __syncthreads();
    if (t < HH) {
      float iv = gls[t], fv = gls[150 + t], gv = gls[300 + t], ov = gls[450 + t];
      creg = fv * creg + iv * gv;
      float nh = ov * tanh_fast(creg);
      H2O[(size_t)ss * 300 + dir * HH + t] = nh;
      ((ushort*)hp)[t] = __half_as_ushort(__float2half(nh));
    }
    __syncthreads();
    xnext = xn;
  }
}

// ---------------- head: logits + log_softmax ----------------
__global__ __launch_bounds__(256, 1) void head_kernel(
    const float* __restrict__ H2O, const float* __restrict__ w_out,
    const float* __restrict__ b_out, float* __restrict__ out)
{
  int s = blockIdx.x * 256 + threadIdx.x;
  if (s >= NS) return;
  float acc[7];
  #pragma unroll
  for (int c = 0; c < 7; ++c) acc[c] = b_out[c];
  const float* hrow = H2O + (size_t)s * 300;
  for (int k = 0; k < 300; ++k) {
    float hv = hrow[k];
    #pragma unroll
    for (int c = 0; c < 7; ++c) acc[c] += hv * w_out[c * 300 + k];
  }
  float m = acc[0];
  #pragma unroll
  for (int c = 1; c < 7; ++c) m = fmaxf(m, acc[c]);
  float sum = 0.f;
  #pragma unroll
  for (int c = 0; c < 7; ++c) sum += __expf(acc[c] - m);
  float lse = m + __logf(sum);
  #pragma unroll
  for (int c = 0; c < 7; ++c) out[s * 7 + c] = acc[c] - lse;
}

extern "C" void kernel_launch(void* const* d_in, const int* in_sizes, int n_in,
                              void* d_out, int out_size, void* d_ws, size_t ws_size,
                              hipStream_t stream) {
  const float* x      = (const float*)d_in[0];
  const float* wif1   = (const float*)d_in[1];
  const float* whf1   = (const float*)d_in[2];
  const float* bif1   = (const float*)d_in[3];
  const float* bhf1   = (const float*)d_in[4];
  const float* wib1   = (const float*)d_in[5];
  const float* whb1   = (const float*)d_in[6];
  const float* bib1   = (const float*)d_in[7];
  const float* bhb1   = (const float*)d_in[8];
  const float* wif2   = (const float*)d_in[9];
  const float* whf2   = (const float*)d_in[10];
  const float* bif2   = (const float*)d_in[11];
  const float* bhf2   = (const float*)d_in[12];
  const float* wib2   = (const float*)d_in[13];
  const float* whb2   = (const float*)d_in[14];
  const float* bib2   = (const float*)d_in[15];
  const float* bhb2   = (const float*)d_in[16];
  const float* w_out  = (const float*)d_in[17];
  const float* b_out  = (const float*)d_in[18];

  char* ws = (char*)d_ws;
  __hip_bfloat16* WXp = (__hip_bfloat16*)(ws + OFF_WXP);
  __hip_bfloat16* WHp = (__hip_bfloat16*)(ws + OFF_WHP);
  float*    B1  = (float*)(ws + OFF_B1);
  _Float16* W2  = (_Float16*)(ws + OFF_W2);
  float*    W2I = (float*)(ws + OFF_W2I);
  float*    SE  = (float*)(ws + OFF_SE);
  float*    XG2 = (float*)(ws + OFF_XG2);
  float*    H2O = (float*)(ws + OFF_H2O);

  prep_kernel<<<(PE4 + 255) / 256, 256, 0, stream>>>(
      wif1, whf1, bif1, bhf1, wib1, whb1, bib1, bhb1,
      wif2, wib2, whf2, whb2, WXp, WHp, B1, W2, W2I);

  (void)hipFuncSetAttribute((const void*)lstm1_kernel,
                            hipFuncAttributeMaxDynamicSharedMemorySize, L1_SMEM);
  lstm1_kernel<<<128, 512, L1_SMEM, stream>>>(x, WXp, WHp, B1, SE);

  xg2_kernel<<<64, 256, 0, stream>>>(SE, W2I, bif2, bhf2, bib2, bhb2, XG2);

  lstm2_kernel<<<2, 640, 0, stream>>>(W2, XG2, H2O);

  head_kernel<<<4, 256, 0, stream>>>(H2O, w_out, b_out, (float*)d_out);
}

// Round 3
// 1874.941 us; speedup vs baseline: 1.3800x; 1.3800x over previous
//
#include <hip/hip_runtime.h>
#include <hip/hip_bf16.h>
#include <hip/hip_fp16.h>

typedef short bf16x8 __attribute__((ext_vector_type(8)));
typedef float f32x4 __attribute__((ext_vector_type(4)));
typedef _Float16 half2v __attribute__((ext_vector_type(2)));
typedef unsigned short u16x4 __attribute__((ext_vector_type(4)));
typedef unsigned int uint32;

#define MFMA_B16(a,b,c) __builtin_amdgcn_mfma_f32_16x16x32_bf16(a,b,c,0,0,0)

// ---------------- geometry ----------------
#define NS   1024
#define TLEN 128
#define DD   343
#define HH   150
#define GG   600
#define KX   352    // padded DD
#define KXP  44
#define KHP  20
#define NP   640    // padded gate dim

// ---------------- ws layout (bytes) ----------------
#define OFF_WXP  0u          // bf16 [2][44][640][8]
#define OFF_WHP  901120u     // bf16 [2][20][640][8]
#define OFF_B1   1310720u    // f32  [2][640]
#define OFF_W2   1315840u    // f16  [2][600][152]
#define OFF_W2I  1680640u    // f32  [2][300][608]
#define OFF_SE   3139840u    // f32  [1024][300]
#define OFF_XG2  4368640u    // f32  [2][1024][600]
#define OFF_H2O  9283840u    // f32  [1024][300]
#define OFF_XBF  10512640u   // bf16 [1024][128][352] = 92274688
#define NEED_BF  102787328ull

// prep section boundaries
#define PE0 450560
#define PE1 655360
#define PE2 656640
#define PE3 839040
#define PE4 1203840

__device__ __forceinline__ float rcp_fast(float x) { return __builtin_amdgcn_rcpf(x); }
__device__ __forceinline__ float sigm(float x) { return rcp_fast(1.f + __expf(-x)); }
__device__ __forceinline__ float tanh_fast(float x) { return 1.f - 2.f * rcp_fast(__expf(2.f * x) + 1.f); }

__device__ __forceinline__ float fdot2u(uint32 a, uint32 b, float c) {
  half2v av = __builtin_bit_cast(half2v, a);
  half2v bv = __builtin_bit_cast(half2v, b);
  return __builtin_amdgcn_fdot2(av, bv, c, false);
}

typedef __attribute__((address_space(1))) const void GASV;
typedef __attribute__((address_space(3))) void LASV;
__device__ __forceinline__ void gload_lds16(const void* g, void* l) {
  __builtin_amdgcn_global_load_lds((GASV*)g, (LASV*)l, 16, 0, 0);
}

// LDS-only barrier: does NOT drain vmcnt, so global_load_lds prefetch stays in flight.
__device__ __forceinline__ void bar_lds() {
  asm volatile("s_waitcnt lgkmcnt(0)" ::: "memory");
  __builtin_amdgcn_s_barrier();
  asm volatile("" ::: "memory");
}
__device__ __forceinline__ void bar_full() {
  asm volatile("s_waitcnt vmcnt(0) lgkmcnt(0)" ::: "memory");
  __builtin_amdgcn_s_barrier();
  asm volatile("" ::: "memory");
}

__device__ __forceinline__ unsigned short f2bu(float v) {
  __hip_bfloat16 b = __float2bfloat16(v);
  return __builtin_bit_cast(unsigned short, b);
}

// ---------------- prep: pack weights ----------------
__global__ __launch_bounds__(256) void prep_kernel(
    const float* __restrict__ wif1, const float* __restrict__ whf1,
    const float* __restrict__ bif1, const float* __restrict__ bhf1,
    const float* __restrict__ wib1, const float* __restrict__ whb1,
    const float* __restrict__ bib1, const float* __restrict__ bhb1,
    const float* __restrict__ wif2, const float* __restrict__ wib2,
    const float* __restrict__ whf2, const float* __restrict__ whb2,
    __hip_bfloat16* __restrict__ WXp, __hip_bfloat16* __restrict__ WHp,
    float* __restrict__ B1, _Float16* __restrict__ W2, float* __restrict__ W2I)
{
  int i = blockIdx.x * 256 + threadIdx.x;
  if (i < PE0) {
    int d = i / 225280; int r = i - d * 225280;
    int p = r / 5120;   int r2 = r - p * 5120;
    int n = r2 >> 3;    int j = r2 & 7;
    int k = p * 8 + j;
    const float* w = d ? wib1 : wif1;
    float v = (n < GG && k < DD) ? w[n * DD + k] : 0.f;
    WXp[i] = __float2bfloat16(v);
  } else if (i < PE1) {
    int ii = i - PE0;
    int d = ii / 102400; int r = ii - d * 102400;
    int p = r / 5120;    int r2 = r - p * 5120;
    int n = r2 >> 3;     int j = r2 & 7;
    int k = p * 8 + j;
    const float* w = d ? whb1 : whf1;
    float v = (n < GG && k < HH) ? w[n * HH + k] : 0.f;
    WHp[ii] = __float2bfloat16(v);
  } else if (i < PE2) {
    int ii = i - PE1;
    int d = ii / NP; int n = ii - d * NP;
    float v = 0.f;
    if (n < GG) v = d ? (bib1[n] + bhb1[n]) : (bif1[n] + bhf1[n]);
    B1[ii] = v;
  } else if (i < PE3) {
    int ii = i - PE2;
    int d = ii / 91200; int r = ii - d * 91200;
    int n = r / 152;    int k = r - n * 152;
    const float* w = d ? whb2 : whf2;
    float v = (k < HH) ? w[n * HH + k] : 0.f;
    W2[ii] = (_Float16)v;
  } else if (i < PE4) {
    int ii = i - PE3;
    int d = ii / 182400; int r = ii - d * 182400;
    int k = r / 608;     int n = r - k * 608;
    const float* w = d ? wib2 : wif2;
    float v = (n < GG) ? w[n * 300 + k] : 0.f;
    W2I[ii] = v;
  }
}

// ---------------- x -> bf16 padded [S][T][352] ----------------
__global__ __launch_bounds__(256) void xcvt_kernel(
    const float* __restrict__ x, __hip_bfloat16* __restrict__ XBF)
{
  const int total4 = NS * TLEN * (KX / 4);   // 11,534,336
  for (int idx = blockIdx.x * 256 + threadIdx.x; idx < total4; idx += gridDim.x * 256) {
    int row = idx / 88;
    int c4 = (idx - row * 88) * 4;
    const float* src = x + (size_t)row * DD + c4;
    float v0 = 0.f, v1 = 0.f, v2 = 0.f, v3 = 0.f;
    if (c4 + 3 < DD) {
      v0 = __builtin_nontemporal_load(src);
      v1 = __builtin_nontemporal_load(src + 1);
      v2 = __builtin_nontemporal_load(src + 2);
      v3 = __builtin_nontemporal_load(src + 3);
    } else {
      if (c4 < DD)     v0 = src[0];
      if (c4 + 1 < DD) v1 = src[1];
      if (c4 + 2 < DD) v2 = src[2];
    }
    u16x4 o;
    o.x = f2bu(v0); o.y = f2bu(v1); o.z = f2bu(v2); o.w = f2bu(v3);
    u16x4* dst = (u16x4*)((unsigned short*)XBF + (size_t)row * KX + c4);
    __builtin_nontemporal_store(o, dst);
  }
}

// ---------------- layer-1 ----------------
// 256 blocks = 128 groups(8 sents) x 2 dirs, 512 threads (8 waves).
// Wave wv owns gate cols [80wv,80wv+80). TB=8 steps = 4 MFMA-row pairs:
// rows 0-7 = step 2p (8 sents), rows 8-15 = step 2p+1. W_hh lives in 100 VGPRs.
#define XS_SZ   45056u                     // bf16 [4][16][352]
#define HS_OFF  (2u * XS_SZ)               // bf16 [16][160] = 5120
#define GS_OFF  (HS_OFF + 5120u)           // f32  [8][604]  = 19328
#define CF_OFF  (GS_OFF + 19328u)          // f32  [8][152]  = 4864
#define MX_OFF  (CF_OFF + 4864u)           // f32  [8][152]  = 4864
#define L1_SMEM (MX_OFF + 4864u)           // 124288

template<bool BF>
__device__ __forceinline__ void stage_x(char* xsd, const float* __restrict__ x,
                                        const __hip_bfloat16* __restrict__ XBF,
                                        int t0, int dir, int s0, int tid, int lane, int wv)
{
  if constexpr (BF) {
    #pragma unroll
    for (int i = 0; i < 6; ++i) {
      int id = i * 8 + wv;
      if (id < 44) {
        int chunk = id * 64 + lane;
        int row16 = chunk / 44;
        int col16 = chunk - row16 * 44;
        int p = row16 >> 4, rr = row16 & 15;
        int t = t0 + 2 * p + (rr >> 3);
        int s = s0 + (rr & 7);
        int tt = dir ? (127 - t) : t;
        const __hip_bfloat16* gp = XBF + ((size_t)s * TLEN + tt) * KX + col16 * 8;
        gload_lds16((const void*)gp, (void*)(xsd + id * 1024));
      }
    }
  } else {
    for (int e = tid; e < 4 * 16 * KX; e += 512) {
      int row16 = e / KX;
      int col = e - row16 * KX;
      int p = row16 >> 4, rr = row16 & 15;
      int t = t0 + 2 * p + (rr >> 3);
      int s = s0 + (rr & 7);
      int tt = dir ? (127 - t) : t;
      float v = (col < DD) ? x[((size_t)s * TLEN + tt) * DD + col] : 0.f;
      ((__hip_bfloat16*)xsd)[e] = __float2bfloat16(v);
    }
  }
}

__device__ __forceinline__ void cell_pass(float* gs, float* cf, float* mx,
                                          __hip_bfloat16* hs, int tid, bool odd)
{
  for (int e = tid; e < 8 * HH; e += 512) {
    int s = e / HH, j = e - s * HH;
    float iv = sigm(gs[s * 604 + j]);
    float fv = sigm(gs[s * 604 + 150 + j]);
    float gv = tanh_fast(gs[s * 604 + 300 + j]);
    float ov = sigm(gs[s * 604 + 450 + j]);
    float c = fv * cf[s * 152 + j] + iv * gv;
    cf[s * 152 + j] = c;
    float h = ov * tanh_fast(c);
    mx[s * 152 + j] = fmaxf(mx[s * 152 + j], h);
    if (odd) {
      hs[s * 160 + j] = __float2bfloat16(h);
      hs[(8 + s) * 160 + j] = __float2bfloat16(0.f);
    } else {
      hs[(8 + s) * 160 + j] = __float2bfloat16(h);
    }
  }
}

template<bool BF>
__global__ __launch_bounds__(512, 2) void lstm1_kernel(
    const float* __restrict__ x, const __hip_bfloat16* __restrict__ XBF,
    const __hip_bfloat16* __restrict__ WXp, const __hip_bfloat16* __restrict__ WHp,
    const float* __restrict__ B1, float* __restrict__ SE)
{
  extern __shared__ char smem[];
  char* xs0 = smem;
  char* xs1 = smem + XS_SZ;
  __hip_bfloat16* hs = (__hip_bfloat16*)(smem + HS_OFF);
  float* gs = (float*)(smem + GS_OFF);
  float* cf = (float*)(smem + CF_OFF);
  float* mx = (float*)(smem + MX_OFF);

  const int tid = threadIdx.x;
  const int lane = tid & 63;
  const int wv = tid >> 6;
  const int dir = blockIdx.x & 1;
  const int s0 = (blockIdx.x >> 1) * 8;
  const int arow = lane & 15;
  const int kgrp = lane >> 4;
  const int nb = wv * 80;

  for (int e = tid; e < 16 * 160; e += 512) hs[e] = __float2bfloat16(0.f);
  for (int e = tid; e < 8 * 152; e += 512) { cf[e] = 0.f; mx[e] = -3e38f; }

  float bias[5];
  #pragma unroll
  for (int nt = 0; nt < 5; ++nt) {
    int n = nb + nt * 16 + arow;
    bias[nt] = (n < GG) ? B1[dir * NP + n] : 0.f;
  }

  const __hip_bfloat16* WXd = WXp + (size_t)dir * KXP * NP * 8;
  const __hip_bfloat16* WHd = WHp + (size_t)dir * KHP * NP * 8;

  bf16x8 whr[5][5];
  #pragma unroll
  for (int kh = 0; kh < 5; ++kh)
    #pragma unroll
    for (int nt = 0; nt < 5; ++nt)
      whr[kh][nt] = *reinterpret_cast<const bf16x8*>(
          WHd + ((size_t)(kh * 4 + kgrp) * NP + nb + nt * 16 + arow) * 8);

  stage_x<BF>(xs0, x, XBF, 0, dir, s0, tid, lane, wv);
  bar_full();

  for (int g = 0; g < 16; ++g) {
    char* xsc = (g & 1) ? xs1 : xs0;
    char* xsn = (g & 1) ? xs0 : xs1;
    const __hip_bfloat16* xsb = (const __hip_bfloat16*)xsc;

    f32x4 acc[4][5];
    #pragma unroll
    for (int p = 0; p < 4; ++p)
      #pragma unroll
      for (int nt = 0; nt < 5; ++nt) acc[p][nt] = (f32x4){0.f, 0.f, 0.f, 0.f};

    // ---- phase A: x-projection, 8 steps folded into 4 row-paired tiles ----
    for (int kk = 0; kk < 11; ++kk) {
      bf16x8 a[4], b[5];
      #pragma unroll
      for (int p = 0; p < 4; ++p)
        a[p] = *reinterpret_cast<const bf16x8*>(xsb + (p * 16 + arow) * KX + kk * 32 + kgrp * 8);
      #pragma unroll
      for (int nt = 0; nt < 5; ++nt)
        b[nt] = *reinterpret_cast<const bf16x8*>(
            WXd + ((size_t)(kk * 4 + kgrp) * NP + nb + nt * 16 + arow) * 8);
      #pragma unroll
      for (int p = 0; p < 4; ++p)
        #pragma unroll
        for (int nt = 0; nt < 5; ++nt)
          acc[p][nt] = MFMA_B16(a[p], b[nt], acc[p][nt]);
    }

    // prefetch next g's x while phase B runs (lands by next bar_full)
    if (g < 15)
      stage_x<BF>(xsn, x, XBF, (g + 1) * 8, dir, s0, tid, lane, wv);

    // ---- phase B: 4 pairs = 8 recurrent steps ----
    #pragma unroll
    for (int p = 0; p < 4; ++p) {
      // MFMA1: rows0-7 += h_{2p-1}*Wh (rows8-15 see zeros)
      #pragma unroll
      for (int kh = 0; kh < 5; ++kh) {
        bf16x8 ah = *reinterpret_cast<const bf16x8*>(hs + arow * 160 + kh * 32 + kgrp * 8);
        #pragma unroll
        for (int nt = 0; nt < 5; ++nt)
          acc[p][nt] = MFMA_B16(ah, whr[kh][nt], acc[p][nt]);
      }
      if (kgrp < 2) {
        #pragma unroll
        for (int nt = 0; nt < 5; ++nt) {
          int n = nb + nt * 16 + arow;
          if (n < GG) {
            #pragma unroll
            for (int r = 0; r < 4; ++r)
              gs[(kgrp * 4 + r) * 604 + n] = acc[p][nt][r] + bias[nt];
          }
        }
      }
      bar_lds();
      cell_pass(gs, cf, mx, hs, tid, false);   // h_{2p} -> hs rows 8-15
      bar_lds();
      // MFMA2: rows8-15 += h_{2p}*Wh (rows0-7 get dead garbage)
      #pragma unroll
      for (int kh = 0; kh < 5; ++kh) {
        bf16x8 ah = *reinterpret_cast<const bf16x8*>(hs + arow * 160 + kh * 32 + kgrp * 8);
        #pragma unroll
        for (int nt = 0; nt < 5; ++nt)
          acc[p][nt] = MFMA_B16(ah, whr[kh][nt], acc[p][nt]);
      }
      if (kgrp >= 2) {
        #pragma unroll
        for (int nt = 0; nt < 5; ++nt) {
          int n = nb + nt * 16 + arow;
          if (n < GG) {
            #pragma unroll
            for (int r = 0; r < 4; ++r)
              gs[((kgrp - 2) * 4 + r) * 604 + n] = acc[p][nt][r] + bias[nt];
          }
        }
      }
      bar_lds();
      cell_pass(gs, cf, mx, hs, tid, true);    // h_{2p+1} -> hs rows 0-7, zero rows 8-15
      if (p == 3) bar_full(); else bar_lds();
    }
  }

  for (int e = tid; e < 8 * HH; e += 512) {
    int s = e / HH, j = e - s * HH;
    SE[(size_t)(s0 + s) * 300 + dir * HH + j] = mx[s * 152 + j];
  }
}

// ---------------- layer-2 input projection ----------------
__global__ __launch_bounds__(256, 1) void xg2_kernel(
    const float* __restrict__ SE, const float* __restrict__ W2I,
    const float* __restrict__ bif2, const float* __restrict__ bhf2,
    const float* __restrict__ bib2, const float* __restrict__ bhb2,
    float* __restrict__ XG2)
{
  __shared__ float se[32 * 304];
  const int d = blockIdx.x >> 5, st = blockIdx.x & 31, sb = st * 32;
  const int tid = threadIdx.x;
  for (int e = tid; e < 32 * 300; e += 256) {
    int si = e / 300, k = e - si * 300;
    se[si * 304 + k] = SE[(size_t)(sb + si) * 300 + k];
  }
  __syncthreads();
  for (int pass = 0; pass < 3; ++pass) {
    int n = pass * 256 + tid;
    if (n < GG) {
      float bias = d ? (bib2[n] + bhb2[n]) : (bif2[n] + bhf2[n]);
      float acc[32];
      #pragma unroll
      for (int si = 0; si < 32; ++si) acc[si] = bias;
      const float* wcol = W2I + (size_t)d * 300 * 608 + n;
      for (int k = 0; k < 300; ++k) {
        float wvv = wcol[(size_t)k * 608];
        #pragma unroll
        for (int si = 0; si < 32; ++si) acc[si] += wvv * se[si * 304 + k];
      }
      #pragma unroll
      for (int si = 0; si < 32; ++si)
        XG2[((size_t)d * NS + sb + si) * GG + n] = acc[si];
    }
  }
}

// ---------------- layer-2 recurrence ----------------
__global__ __launch_bounds__(640, 3) void lstm2_kernel(
    const _Float16* __restrict__ W2, const float* __restrict__ XG2,
    float* __restrict__ H2O)
{
  const int dir = blockIdx.x;
  const int t = threadIdx.x;
  __shared__ float gls[GG];
  __shared__ __align__(16) uint32 hp[80];

  uint32 w2p[76];
  if (t < GG) {
    const uint32* wr = (const uint32*)(W2 + ((size_t)dir * GG + t) * 152);
    #pragma unroll
    for (int q = 0; q < 76; ++q) w2p[q] = wr[q];
  }
  if (t < 80) hp[t] = 0u;
  __syncthreads();

  float creg = 0.f;
  const float* xg = XG2 + (size_t)dir * NS * GG;
  int ss0 = dir ? 1023 : 0;
  float xnext = (t < GG) ? xg[(size_t)ss0 * GG + t] : 0.f;

  for (int step = 0; step < 1024; ++step) {
    const int ss = dir ? (1023 - step) : step;
    float xn = 0.f;
    if (step < 1023 && t < GG) {
      int ss2 = dir ? (1022 - step) : (step + 1);
      xn = xg[(size_t)ss2 * GG + t];
    }
    if (t < GG) {
      const uint4* hp4 = reinterpret_cast<const uint4*>(hp);
      float a0 = xnext, a1 = 0.f, a2 = 0.f, a3 = 0.f;
      #pragma unroll
      for (int q4 = 0; q4 < 19; ++q4) {
        uint4 hv = hp4[q4];
        a0 = fdot2u(hv.x, w2p[q4 * 4 + 0], a0);
        a1 = fdot2u(hv.y, w2p[q4 * 4 + 1], a1);
        a2 = fdot2u(hv.z, w2p[q4 * 4 + 2], a2);
        a3 = fdot2u(hv.w, w2p[q4 * 4 + 3], a3);
      }
      float acc = (a0 + a1) + (a2 + a3);
      bool isg = (t >= 300) && (t < 450);
      gls[t] = isg ? tanh_fast(acc) : sigm(acc);
    }
    bar_lds();
    if (t < HH) {
      float iv = gls[t], fv = gls[150 + t], gv = gls[300 + t], ov = gls[450 + t];
      creg = fv * creg + iv * gv;
      float nh = ov * tanh_fast(creg);
      H2O[(size_t)ss * 300 + dir * HH + t] = nh;
      ((ushort*)hp)[t] = __half_as_ushort(__float2half(nh));
    }
    bar_lds();
    xnext = xn;
  }
}

// ---------------- head ----------------
__global__ __launch_bounds__(256, 1) void head_kernel(
    const float* __restrict__ H2O, const float* __restrict__ w_out,
    const float* __restrict__ b_out, float* __restrict__ out)
{
  int s = blockIdx.x * 256 + threadIdx.x;
  if (s >= NS) return;
  float acc[7];
  #pragma unroll
  for (int c = 0; c < 7; ++c) acc[c] = b_out[c];
  const float* hrow = H2O + (size_t)s * 300;
  for (int k = 0; k < 300; ++k) {
    float hv = hrow[k];
    #pragma unroll
    for (int c = 0; c < 7; ++c) acc[c] += hv * w_out[c * 300 + k];
  }
  float m = acc[0];
  #pragma unroll
  for (int c = 1; c < 7; ++c) m = fmaxf(m, acc[c]);
  float sum = 0.f;
  #pragma unroll
  for (int c = 0; c < 7; ++c) sum += __expf(acc[c] - m);
  float lse = m + __logf(sum);
  #pragma unroll
  for (int c = 0; c < 7; ++c) out[s * 7 + c] = acc[c] - lse;
}

extern "C" void kernel_launch(void* const* d_in, const int* in_sizes, int n_in,
                              void* d_out, int out_size, void* d_ws, size_t ws_size,
                              hipStream_t stream) {
  const float* x      = (const float*)d_in[0];
  const float* wif1   = (const float*)d_in[1];
  const float* whf1   = (const float*)d_in[2];
  const float* bif1   = (const float*)d_in[3];
  const float* bhf1   = (const float*)d_in[4];
  const float* wib1   = (const float*)d_in[5];
  const float* whb1   = (const float*)d_in[6];
  const float* bib1   = (const float*)d_in[7];
  const float* bhb1   = (const float*)d_in[8];
  const float* wif2   = (const float*)d_in[9];
  const float* whf2   = (const float*)d_in[10];
  const float* bif2   = (const float*)d_in[11];
  const float* bhf2   = (const float*)d_in[12];
  const float* wib2   = (const float*)d_in[13];
  const float* whb2   = (const float*)d_in[14];
  const float* bib2   = (const float*)d_in[15];
  const float* bhb2   = (const float*)d_in[16];
  const float* w_out  = (const float*)d_in[17];
  const float* b_out  = (const float*)d_in[18];

  char* ws = (char*)d_ws;
  __hip_bfloat16* WXp = (__hip_bfloat16*)(ws + OFF_WXP);
  __hip_bfloat16* WHp = (__hip_bfloat16*)(ws + OFF_WHP);
  float*    B1  = (float*)(ws + OFF_B1);
  _Float16* W2  = (_Float16*)(ws + OFF_W2);
  float*    W2I = (float*)(ws + OFF_W2I);
  float*    SE  = (float*)(ws + OFF_SE);
  float*    XG2 = (float*)(ws + OFF_XG2);
  float*    H2O = (float*)(ws + OFF_H2O);
  __hip_bfloat16* XBF = (__hip_bfloat16*)(ws + OFF_XBF);

  const bool useBF = (ws_size >= NEED_BF);

  prep_kernel<<<(PE4 + 255) / 256, 256, 0, stream>>>(
      wif1, whf1, bif1, bhf1, wib1, whb1, bib1, bhb1,
      wif2, wib2, whf2, whb2, WXp, WHp, B1, W2, W2I);

  if (useBF)
    xcvt_kernel<<<4096, 256, 0, stream>>>(x, XBF);

  (void)hipFuncSetAttribute((const void*)(lstm1_kernel<true>),
                            hipFuncAttributeMaxDynamicSharedMemorySize, L1_SMEM);
  (void)hipFuncSetAttribute((const void*)(lstm1_kernel<false>),
                            hipFuncAttributeMaxDynamicSharedMemorySize, L1_SMEM);

  if (useBF)
    lstm1_kernel<true><<<256, 512, L1_SMEM, stream>>>(x, XBF, WXp, WHp, B1, SE);
  else
    lstm1_kernel<false><<<256, 512, L1_SMEM, stream>>>(x, XBF, WXp, WHp, B1, SE);

  xg2_kernel<<<64, 256, 0, stream>>>(SE, W2I, bif2, bhf2, bib2, bhb2, XG2);

  lstm2_kernel<<<2, 640, 0, stream>>>(W2, XG2, H2O);

  head_kernel<<<4, 256, 0, stream>>>(H2O, w_out, b_out, (float*)d_out);
}

// Round 4
// 1690.256 us; speedup vs baseline: 1.5308x; 1.1093x over previous
//
#include <hip/hip_runtime.h>
#include <hip/hip_bf16.h>
#include <hip/hip_fp16.h>

typedef short bf16x8 __attribute__((ext_vector_type(8)));
typedef float f32x4 __attribute__((ext_vector_type(4)));
typedef _Float16 half2v __attribute__((ext_vector_type(2)));
typedef unsigned short u16x4 __attribute__((ext_vector_type(4)));
typedef unsigned int uint32;

#define MFMA_B16(a,b,c) __builtin_amdgcn_mfma_f32_16x16x32_bf16(a,b,c,0,0,0)

// ---------------- geometry ----------------
#define NS   1024
#define TLEN 128
#define DD   343
#define HH   150
#define GG   600
#define KX   352    // padded DD
#define KXP  44
#define KHP  20
#define NP   640    // padded gate dim

// ---------------- ws layout (bytes) ----------------
#define OFF_WXP  0u          // bf16 [2][44][640][8]
#define OFF_WHP  901120u     // bf16 [2][20][640][8]
#define OFF_B1   1310720u    // f32  [2][640]
#define OFF_W2   1315840u    // f16  [2][600][152]
#define OFF_W2I  1680640u    // f32  [2][300][608]
#define OFF_SE   3139840u    // f32  [1024][300]
#define OFF_XG2  4368640u    // f32  [2][1024][600]
#define OFF_H2O  9283840u    // f32  [1024][300]
#define OFF_XBF  10512640u   // bf16 [1024][128][352] = 92274688
#define NEED_BF  102787328ull

// prep section boundaries
#define PE0 450560
#define PE1 655360
#define PE2 656640
#define PE3 839040
#define PE4 1203840

__device__ __forceinline__ float rcp_fast(float x) { return __builtin_amdgcn_rcpf(x); }
__device__ __forceinline__ float sigm(float x) { return rcp_fast(1.f + __expf(-x)); }
__device__ __forceinline__ float tanh_fast(float x) { return 1.f - 2.f * rcp_fast(__expf(2.f * x) + 1.f); }

__device__ __forceinline__ float fdot2u(uint32 a, uint32 b, float c) {
  half2v av = __builtin_bit_cast(half2v, a);
  half2v bv = __builtin_bit_cast(half2v, b);
  return __builtin_amdgcn_fdot2(av, bv, c, false);
}

typedef __attribute__((address_space(1))) const void GASV;
typedef __attribute__((address_space(3))) void LASV;
__device__ __forceinline__ void gload_lds16(const void* g, void* l) {
  __builtin_amdgcn_global_load_lds((GASV*)g, (LASV*)l, 16, 0, 0);
}

// LDS-only barrier: does NOT drain vmcnt, so global_load_lds prefetch stays in flight.
__device__ __forceinline__ void bar_lds() {
  asm volatile("s_waitcnt lgkmcnt(0)" ::: "memory");
  __builtin_amdgcn_s_barrier();
  asm volatile("" ::: "memory");
}
__device__ __forceinline__ void bar_full() {
  asm volatile("s_waitcnt vmcnt(0) lgkmcnt(0)" ::: "memory");
  __builtin_amdgcn_s_barrier();
  asm volatile("" ::: "memory");
}

__device__ __forceinline__ unsigned short f2bu(float v) {
  __hip_bfloat16 b = __float2bfloat16(v);
  return __builtin_bit_cast(unsigned short, b);
}

// ---------------- prep: pack weights ----------------
__global__ __launch_bounds__(256) void prep_kernel(
    const float* __restrict__ wif1, const float* __restrict__ whf1,
    const float* __restrict__ bif1, const float* __restrict__ bhf1,
    const float* __restrict__ wib1, const float* __restrict__ whb1,
    const float* __restrict__ bib1, const float* __restrict__ bhb1,
    const float* __restrict__ wif2, const float* __restrict__ wib2,
    const float* __restrict__ whf2, const float* __restrict__ whb2,
    __hip_bfloat16* __restrict__ WXp, __hip_bfloat16* __restrict__ WHp,
    float* __restrict__ B1, _Float16* __restrict__ W2, float* __restrict__ W2I)
{
  int i = blockIdx.x * 256 + threadIdx.x;
  if (i < PE0) {
    int d = i / 225280; int r = i - d * 225280;
    int p = r / 5120;   int r2 = r - p * 5120;
    int n = r2 >> 3;    int j = r2 & 7;
    int k = p * 8 + j;
    const float* w = d ? wib1 : wif1;
    float v = (n < GG && k < DD) ? w[n * DD + k] : 0.f;
    WXp[i] = __float2bfloat16(v);
  } else if (i < PE1) {
    int ii = i - PE0;
    int d = ii / 102400; int r = ii - d * 102400;
    int p = r / 5120;    int r2 = r - p * 5120;
    int n = r2 >> 3;     int j = r2 & 7;
    int k = p * 8 + j;
    const float* w = d ? whb1 : whf1;
    float v = (n < GG && k < HH) ? w[n * HH + k] : 0.f;
    WHp[ii] = __float2bfloat16(v);
  } else if (i < PE2) {
    int ii = i - PE1;
    int d = ii / NP; int n = ii - d * NP;
    float v = 0.f;
    if (n < GG) v = d ? (bib1[n] + bhb1[n]) : (bif1[n] + bhf1[n]);
    B1[ii] = v;
  } else if (i < PE3) {
    int ii = i - PE2;
    int d = ii / 91200; int r = ii - d * 91200;
    int n = r / 152;    int k = r - n * 152;
    const float* w = d ? whb2 : whf2;
    float v = (k < HH) ? w[n * HH + k] : 0.f;
    W2[ii] = (_Float16)v;
  } else if (i < PE4) {
    int ii = i - PE3;
    int d = ii / 182400; int r = ii - d * 182400;
    int k = r / 608;     int n = r - k * 608;
    const float* w = d ? wib2 : wif2;
    float v = (n < GG) ? w[n * 300 + k] : 0.f;
    W2I[ii] = v;
  }
}

// ---------------- x -> bf16 padded [S][T][352] ----------------
__global__ __launch_bounds__(256) void xcvt_kernel(
    const float* __restrict__ x, __hip_bfloat16* __restrict__ XBF)
{
  const int total4 = NS * TLEN * (KX / 4);   // 11,534,336
  for (int idx = blockIdx.x * 256 + threadIdx.x; idx < total4; idx += gridDim.x * 256) {
    int row = idx / 88;
    int c4 = (idx - row * 88) * 4;
    const float* src = x + (size_t)row * DD + c4;
    float v0 = 0.f, v1 = 0.f, v2 = 0.f, v3 = 0.f;
    if (c4 + 3 < DD) {
      v0 = __builtin_nontemporal_load(src);
      v1 = __builtin_nontemporal_load(src + 1);
      v2 = __builtin_nontemporal_load(src + 2);
      v3 = __builtin_nontemporal_load(src + 3);
    } else {
      if (c4 < DD)     v0 = src[0];
      if (c4 + 1 < DD) v1 = src[1];
      if (c4 + 2 < DD) v2 = src[2];
    }
    u16x4 o;
    o.x = f2bu(v0); o.y = f2bu(v1); o.z = f2bu(v2); o.w = f2bu(v3);
    u16x4* dst = (u16x4*)((unsigned short*)XBF + (size_t)row * KX + c4);
    __builtin_nontemporal_store(o, dst);
  }
}

// ---------------- layer-1 ----------------
// 256 blocks = 128 groups(8 sents) x 2 dirs, 512 threads (8 waves).
// Wave wv owns gate cols [80wv,80wv+80). TB=8 steps = 4 MFMA-row pairs:
// rows 0-7 = step 2p (8 sents), rows 8-15 = step 2p+1. W_hh pinned in 100 VGPRs.
#define XS_SZ   45056u                     // bf16 [4][16][352]
#define HS_OFF  (2u * XS_SZ)               // bf16 [16][160] = 5120
#define GS_OFF  (HS_OFF + 5120u)           // f32  [8][604]  = 19328
#define CF_OFF  (GS_OFF + 19328u)          // f32  [8][152]  = 4864
#define MX_OFF  (CF_OFF + 4864u)           // f32  [8][152]  = 4864
#define L1_SMEM (MX_OFF + 4864u)           // 124288

template<bool BF>
__device__ __forceinline__ void stage_x(char* xsd, const float* __restrict__ x,
                                        const __hip_bfloat16* __restrict__ XBF,
                                        int t0, int dir, int s0, int tid, int lane, int wv)
{
  if constexpr (BF) {
    #pragma unroll
    for (int i = 0; i < 6; ++i) {
      int id = i * 8 + wv;
      if (id < 44) {
        int chunk = id * 64 + lane;
        int row16 = chunk / 44;
        int col16 = chunk - row16 * 44;
        int p = row16 >> 4, rr = row16 & 15;
        int t = t0 + 2 * p + (rr >> 3);
        int s = s0 + (rr & 7);
        int tt = dir ? (127 - t) : t;
        const __hip_bfloat16* gp = XBF + ((size_t)s * TLEN + tt) * KX + col16 * 8;
        gload_lds16((const void*)gp, (void*)(xsd + id * 1024));
      }
    }
  } else {
    for (int e = tid; e < 4 * 16 * KX; e += 512) {
      int row16 = e / KX;
      int col = e - row16 * KX;
      int p = row16 >> 4, rr = row16 & 15;
      int t = t0 + 2 * p + (rr >> 3);
      int s = s0 + (rr & 7);
      int tt = dir ? (127 - t) : t;
      float v = (col < DD) ? x[((size_t)s * TLEN + tt) * DD + col] : 0.f;
      ((__hip_bfloat16*)xsd)[e] = __float2bfloat16(v);
    }
  }
}

__device__ __forceinline__ void cell_pass(float* gs, float* cf, float* mx,
                                          __hip_bfloat16* hs, int tid, bool odd)
{
  for (int e = tid; e < 8 * HH; e += 512) {
    int s = e / HH, j = e - s * HH;
    float iv = sigm(gs[s * 604 + j]);
    float fv = sigm(gs[s * 604 + 150 + j]);
    float gv = tanh_fast(gs[s * 604 + 300 + j]);
    float ov = sigm(gs[s * 604 + 450 + j]);
    float c = fv * cf[s * 152 + j] + iv * gv;
    cf[s * 152 + j] = c;
    float h = ov * tanh_fast(c);
    mx[s * 152 + j] = fmaxf(mx[s * 152 + j], h);
    if (odd) {
      hs[s * 160 + j] = __float2bfloat16(h);
      hs[(8 + s) * 160 + j] = __float2bfloat16(0.f);
    } else {
      hs[(8 + s) * 160 + j] = __float2bfloat16(h);
    }
  }
}

template<bool BF>
__global__ __launch_bounds__(512, 2) void lstm1_kernel(
    const float* __restrict__ x, const __hip_bfloat16* __restrict__ XBF,
    const __hip_bfloat16* __restrict__ WXp, const __hip_bfloat16* __restrict__ WHp,
    const float* __restrict__ B1, float* __restrict__ SE)
{
  extern __shared__ char smem[];
  char* xs0 = smem;
  char* xs1 = smem + XS_SZ;
  __hip_bfloat16* hs = (__hip_bfloat16*)(smem + HS_OFF);
  float* gs = (float*)(smem + GS_OFF);
  float* cf = (float*)(smem + CF_OFF);
  float* mx = (float*)(smem + MX_OFF);

  const int tid = threadIdx.x;
  const int lane = tid & 63;
  const int wv = tid >> 6;
  const int dir = blockIdx.x & 1;
  const int s0 = (blockIdx.x >> 1) * 8;
  const int arow = lane & 15;
  const int kgrp = lane >> 4;
  const int nb = wv * 80;

  for (int e = tid; e < 16 * 160; e += 512) hs[e] = __float2bfloat16(0.f);
  for (int e = tid; e < 8 * 152; e += 512) { cf[e] = 0.f; mx[e] = -3e38f; }

  float bias[5];
  #pragma unroll
  for (int nt = 0; nt < 5; ++nt) {
    int n = nb + nt * 16 + arow;
    bias[nt] = (n < GG) ? B1[dir * NP + n] : 0.f;
    asm volatile("" : "+v"(bias[nt]));
  }

  const __hip_bfloat16* WXd = WXp + (size_t)dir * KXP * NP * 8;
  const __hip_bfloat16* WHd = WHp + (size_t)dir * KHP * NP * 8;

  bf16x8 whr[5][5];
  #pragma unroll
  for (int kh = 0; kh < 5; ++kh)
    #pragma unroll
    for (int nt = 0; nt < 5; ++nt)
      whr[kh][nt] = *reinterpret_cast<const bf16x8*>(
          WHd + ((size_t)(kh * 4 + kgrp) * NP + nb + nt * 16 + arow) * 8);
  // pin W_hh fragments in VGPRs: the barrier asm's "memory" clobber would
  // otherwise let the compiler rematerialize these loads inside the loop
  #pragma unroll
  for (int kh = 0; kh < 5; ++kh)
    #pragma unroll
    for (int nt = 0; nt < 5; ++nt)
      asm volatile("" : "+v"(whr[kh][nt]));

  stage_x<BF>(xs0, x, XBF, 0, dir, s0, tid, lane, wv);
  bar_full();

  for (int g = 0; g < 16; ++g) {
    char* xsc = (g & 1) ? xs1 : xs0;
    char* xsn = (g & 1) ? xs0 : xs1;
    const __hip_bfloat16* xsb = (const __hip_bfloat16*)xsc;

    f32x4 acc[4][5];
    #pragma unroll
    for (int p = 0; p < 4; ++p)
      #pragma unroll
      for (int nt = 0; nt < 5; ++nt) acc[p][nt] = (f32x4){0.f, 0.f, 0.f, 0.f};

    // ---- phase A: x-projection, 8 steps folded into 4 row-paired tiles ----
    for (int kk = 0; kk < 11; ++kk) {
      bf16x8 a[4], b[5];
      #pragma unroll
      for (int p = 0; p < 4; ++p)
        a[p] = *reinterpret_cast<const bf16x8*>(xsb + (p * 16 + arow) * KX + kk * 32 + kgrp * 8);
      #pragma unroll
      for (int nt = 0; nt < 5; ++nt)
        b[nt] = *reinterpret_cast<const bf16x8*>(
            WXd + ((size_t)(kk * 4 + kgrp) * NP + nb + nt * 16 + arow) * 8);
      #pragma unroll
      for (int p = 0; p < 4; ++p)
        #pragma unroll
        for (int nt = 0; nt < 5; ++nt)
          acc[p][nt] = MFMA_B16(a[p], b[nt], acc[p][nt]);
    }

    // prefetch next g's x while phase B runs (lands by next bar_full)
    if (g < 15)
      stage_x<BF>(xsn, x, XBF, (g + 1) * 8, dir, s0, tid, lane, wv);

    // ---- phase B: 4 pairs = 8 recurrent steps ----
    #pragma unroll
    for (int p = 0; p < 4; ++p) {
      // MFMA1: rows0-7 += h_{2p-1}*Wh (rows8-15 see zeros)
      #pragma unroll
      for (int kh = 0; kh < 5; ++kh) {
        bf16x8 ah = *reinterpret_cast<const bf16x8*>(hs + arow * 160 + kh * 32 + kgrp * 8);
        #pragma unroll
        for (int nt = 0; nt < 5; ++nt)
          acc[p][nt] = MFMA_B16(ah, whr[kh][nt], acc[p][nt]);
      }
      if (kgrp < 2) {
        #pragma unroll
        for (int nt = 0; nt < 5; ++nt) {
          int n = nb + nt * 16 + arow;
          if (n < GG) {
            #pragma unroll
            for (int r = 0; r < 4; ++r)
              gs[(kgrp * 4 + r) * 604 + n] = acc[p][nt][r] + bias[nt];
          }
        }
      }
      bar_lds();
      cell_pass(gs, cf, mx, hs, tid, false);   // h_{2p} -> hs rows 8-15
      bar_lds();
      // MFMA2: rows8-15 += h_{2p}*Wh (rows0-7 get dead garbage)
      #pragma unroll
      for (int kh = 0; kh < 5; ++kh) {
        bf16x8 ah = *reinterpret_cast<const bf16x8*>(hs + arow * 160 + kh * 32 + kgrp * 8);
        #pragma unroll
        for (int nt = 0; nt < 5; ++nt)
          acc[p][nt] = MFMA_B16(ah, whr[kh][nt], acc[p][nt]);
      }
      if (kgrp >= 2) {
        #pragma unroll
        for (int nt = 0; nt < 5; ++nt) {
          int n = nb + nt * 16 + arow;
          if (n < GG) {
            #pragma unroll
            for (int r = 0; r < 4; ++r)
              gs[((kgrp - 2) * 4 + r) * 604 + n] = acc[p][nt][r] + bias[nt];
          }
        }
      }
      bar_lds();
      cell_pass(gs, cf, mx, hs, tid, true);    // h_{2p+1} -> hs rows 0-7, zero rows 8-15
      if (p == 3) bar_full(); else bar_lds();
    }
  }

  for (int e = tid; e < 8 * HH; e += 512) {
    int s = e / HH, j = e - s * HH;
    SE[(size_t)(s0 + s) * 300 + dir * HH + j] = mx[s * 152 + j];
  }
}

// ---------------- layer-2 input projection ----------------
__global__ __launch_bounds__(256, 1) void xg2_kernel(
    const float* __restrict__ SE, const float* __restrict__ W2I,
    const float* __restrict__ bif2, const float* __restrict__ bhf2,
    const float* __restrict__ bib2, const float* __restrict__ bhb2,
    float* __restrict__ XG2)
{
  __shared__ float se[32 * 304];
  const int d = blockIdx.x >> 5, st = blockIdx.x & 31, sb = st * 32;
  const int tid = threadIdx.x;
  for (int e = tid; e < 32 * 300; e += 256) {
    int si = e / 300, k = e - si * 300;
    se[si * 304 + k] = SE[(size_t)(sb + si) * 300 + k];
  }
  __syncthreads();
  for (int pass = 0; pass < 3; ++pass) {
    int n = pass * 256 + tid;
    if (n < GG) {
      float bias = d ? (bib2[n] + bhb2[n]) : (bif2[n] + bhf2[n]);
      float acc[32];
      #pragma unroll
      for (int si = 0; si < 32; ++si) acc[si] = bias;
      const float* wcol = W2I + (size_t)d * 300 * 608 + n;
      for (int k = 0; k < 300; ++k) {
        float wvv = wcol[(size_t)k * 608];
        #pragma unroll
        for (int si = 0; si < 32; ++si) acc[si] += wvv * se[si * 304 + k];
      }
      #pragma unroll
      for (int si = 0; si < 32; ++si)
        XG2[((size_t)d * NS + sb + si) * GG + n] = acc[si];
    }
  }
}

// ---------------- layer-2 recurrence: weights PINNED in VGPRs ----------------
__global__ __launch_bounds__(640) void lstm2_kernel(
    const _Float16* __restrict__ W2, const float* __restrict__ XG2,
    float* __restrict__ H2O)
{
  const int dir = blockIdx.x;
  const int t = threadIdx.x;
  const int tr = (t < GG) ? t : (GG - 1);   // clamped row: no divergence below
  __shared__ float gls[640];
  __shared__ __align__(16) uint32 hp[80];

  uint32 w2p[76];
  {
    const uint32* wr = (const uint32*)(W2 + ((size_t)dir * GG + tr) * 152);
    #pragma unroll
    for (int q = 0; q < 76; ++q) w2p[q] = wr[q];
  }
  // pin: barrier asm's "memory" clobber must not cause per-step reloads
  #pragma unroll
  for (int q = 0; q < 76; ++q) asm volatile("" : "+v"(w2p[q]));

  if (t < 80) hp[t] = 0u;
  __syncthreads();

  float creg = 0.f;
  const float* xg = XG2 + (size_t)dir * NS * GG;
  const bool isg = (t >= 300) && (t < 450);
  float xnext = xg[(size_t)(dir ? 1023 : 0) * GG + tr];

  for (int step = 0; step < 1024; ++step) {
    const int ss = dir ? (1023 - step) : step;
    float xn = 0.f;
    if (step < 1023) {
      int ss2 = dir ? (1022 - step) : (step + 1);
      xn = xg[(size_t)ss2 * GG + tr];
    }
    const uint4* hp4 = reinterpret_cast<const uint4*>(hp);
    float a0 = xnext, a1 = 0.f, a2 = 0.f, a3 = 0.f;
    #pragma unroll
    for (int q4 = 0; q4 < 19; ++q4) {
      uint4 hv = hp4[q4];
      a0 = fdot2u(hv.x, w2p[q4 * 4 + 0], a0);
      a1 = fdot2u(hv.y, w2p[q4 * 4 + 1], a1);
      a2 = fdot2u(hv.z, w2p[q4 * 4 + 2], a2);
      a3 = fdot2u(hv.w, w2p[q4 * 4 + 3], a3);
    }
    float acc = (a0 + a1) + (a2 + a3);
    gls[t] = isg ? tanh_fast(acc) : sigm(acc);
    bar_lds();
    if (t < HH) {
      float iv = gls[t], fv = gls[150 + t], gv = gls[300 + t], ov = gls[450 + t];
      creg = fv * creg + iv * gv;
      float nh = ov * tanh_fast(creg);
      H2O[(size_t)ss * 300 + dir * HH + t] = nh;
      ((ushort*)hp)[t] = __half_as_ushort(__float2half(nh));
    }
    bar_lds();
    xnext = xn;
  }
}

// ---------------- head ----------------
__global__ __launch_bounds__(256, 1) void head_kernel(
    const float* __restrict__ H2O, const float* __restrict__ w_out,
    const float* __restrict__ b_out, float* __restrict__ out)
{
  int s = blockIdx.x * 256 + threadIdx.x;
  if (s >= NS) return;
  float acc[7];
  #pragma unroll
  for (int c = 0; c < 7; ++c) acc[c] = b_out[c];
  const float* hrow = H2O + (size_t)s * 300;
  for (int k = 0; k < 300; ++k) {
    float hv = hrow[k];
    #pragma unroll
    for (int c = 0; c < 7; ++c) acc[c] += hv * w_out[c * 300 + k];
  }
  float m = acc[0];
  #pragma unroll
  for (int c = 1; c < 7; ++c) m = fmaxf(m, acc[c]);
  float sum = 0.f;
  #pragma unroll
  for (int c = 0; c < 7; ++c) sum += __expf(acc[c] - m);
  float lse = m + __logf(sum);
  #pragma unroll
  for (int c = 0; c < 7; ++c) out[s * 7 + c] = acc[c] - lse;
}

extern "C" void kernel_launch(void* const* d_in, const int* in_sizes, int n_in,
                              void* d_out, int out_size, void* d_ws, size_t ws_size,
                              hipStream_t stream) {
  const float* x      = (const float*)d_in[0];
  const float* wif1   = (const float*)d_in[1];
  const float* whf1   = (const float*)d_in[2];
  const float* bif1   = (const float*)d_in[3];
  const float* bhf1   = (const float*)d_in[4];
  const float* wib1   = (const float*)d_in[5];
  const float* whb1   = (const float*)d_in[6];
  const float* bib1   = (const float*)d_in[7];
  const float* bhb1   = (const float*)d_in[8];
  const float* wif2   = (const float*)d_in[9];
  const float* whf2   = (const float*)d_in[10];
  const float* bif2   = (const float*)d_in[11];
  const float* bhf2   = (const float*)d_in[12];
  const float* wib2   = (const float*)d_in[13];
  const float* whb2   = (const float*)d_in[14];
  const float* bib2   = (const float*)d_in[15];
  const float* bhb2   = (const float*)d_in[16];
  const float* w_out  = (const float*)d_in[17];
  const float* b_out  = (const float*)d_in[18];

  char* ws = (char*)d_ws;
  __hip_bfloat16* WXp = (__hip_bfloat16*)(ws + OFF_WXP);
  __hip_bfloat16* WHp = (__hip_bfloat16*)(ws + OFF_WHP);
  float*    B1  = (float*)(ws + OFF_B1);
  _Float16* W2  = (_Float16*)(ws + OFF_W2);
  float*    W2I = (float*)(ws + OFF_W2I);
  float*    SE  = (float*)(ws + OFF_SE);
  float*    XG2 = (float*)(ws + OFF_XG2);
  float*    H2O = (float*)(ws + OFF_H2O);
  __hip_bfloat16* XBF = (__hip_bfloat16*)(ws + OFF_XBF);

  const bool useBF = (ws_size >= NEED_BF);

  prep_kernel<<<(PE4 + 255) / 256, 256, 0, stream>>>(
      wif1, whf1, bif1, bhf1, wib1, whb1, bib1, bhb1,
      wif2, wib2, whf2, whb2, WXp, WHp, B1, W2, W2I);

  if (useBF)
    xcvt_kernel<<<4096, 256, 0, stream>>>(x, XBF);

  (void)hipFuncSetAttribute((const void*)(lstm1_kernel<true>),
                            hipFuncAttributeMaxDynamicSharedMemorySize, L1_SMEM);
  (void)hipFuncSetAttribute((const void*)(lstm1_kernel<false>),
                            hipFuncAttributeMaxDynamicSharedMemorySize, L1_SMEM);

  if (useBF)
    lstm1_kernel<true><<<256, 512, L1_SMEM, stream>>>(x, XBF, WXp, WHp, B1, SE);
  else
    lstm1_kernel<false><<<256, 512, L1_SMEM, stream>>>(x, XBF, WXp, WHp, B1, SE);

  xg2_kernel<<<64, 256, 0, stream>>>(SE, W2I, bif2, bhf2, bib2, bhb2, XG2);

  lstm2_kernel<<<2, 640, 0, stream>>>(W2, XG2, H2O);

  head_kernel<<<4, 256, 0, stream>>>(H2O, w_out, b_out, (float*)d_out);
}

// Round 5
// 1665.969 us; speedup vs baseline: 1.5531x; 1.0146x over previous
//
#include <hip/hip_runtime.h>
#include <hip/hip_bf16.h>
#include <hip/hip_fp16.h>

typedef short bf16x8 __attribute__((ext_vector_type(8)));
typedef float f32x4 __attribute__((ext_vector_type(4)));
typedef _Float16 half2v __attribute__((ext_vector_type(2)));
typedef unsigned short u16x4 __attribute__((ext_vector_type(4)));
typedef unsigned int u32x4v __attribute__((ext_vector_type(4)));
typedef unsigned int uint32;

#define MFMA_B16(a,b,c) __builtin_amdgcn_mfma_f32_16x16x32_bf16(a,b,c,0,0,0)

// ---------------- geometry ----------------
#define NS   1024
#define TLEN 128
#define DD   343
#define HH   150
#define GG   600
#define KX   352    // padded DD
#define KXP  44
#define KHP  20
#define NP   640    // padded gate dim

// ---------------- ws layout (bytes) ----------------
#define OFF_WXP  0u          // bf16 [2][44][640][8]
#define OFF_WHP  901120u     // bf16 [2][20][640][8]
#define OFF_B1   1310720u    // f32  [2][640]
#define OFF_W2   1315840u    // f16  [2][600][152]
#define OFF_W2I  1680640u    // f32  [2][300][608]
#define OFF_SE   3139840u    // f32  [1024][300]
#define OFF_XG2  4368640u    // f32  [2][1024][600]
#define OFF_H2O  9283840u    // f32  [1024][300]
#define OFF_XBF  10512640u   // bf16 [1024][128][352] = 92274688
#define NEED_BF  102787328ull

// prep section boundaries
#define PE0 450560
#define PE1 655360
#define PE2 656640
#define PE3 839040
#define PE4 1203840

__device__ __forceinline__ float rcp_fast(float x) { return __builtin_amdgcn_rcpf(x); }
__device__ __forceinline__ float sigm(float x) { return rcp_fast(1.f + __expf(-x)); }
__device__ __forceinline__ float tanh_fast(float x) { return 1.f - 2.f * rcp_fast(__expf(2.f * x) + 1.f); }

__device__ __forceinline__ float fdot2u(uint32 a, uint32 b, float c) {
  half2v av = __builtin_bit_cast(half2v, a);
  half2v bv = __builtin_bit_cast(half2v, b);
  return __builtin_amdgcn_fdot2(av, bv, c, false);
}

typedef __attribute__((address_space(1))) const void GASV;
typedef __attribute__((address_space(3))) void LASV;
__device__ __forceinline__ void gload_lds16(const void* g, void* l) {
  __builtin_amdgcn_global_load_lds((GASV*)g, (LASV*)l, 16, 0, 0);
}

// LDS-only barrier: does NOT drain vmcnt, so global_load_lds prefetch stays in flight.
__device__ __forceinline__ void bar_lds() {
  asm volatile("s_waitcnt lgkmcnt(0)" ::: "memory");
  __builtin_amdgcn_s_barrier();
  asm volatile("" ::: "memory");
}
__device__ __forceinline__ void bar_full() {
  asm volatile("s_waitcnt vmcnt(0) lgkmcnt(0)" ::: "memory");
  __builtin_amdgcn_s_barrier();
  asm volatile("" ::: "memory");
}

__device__ __forceinline__ unsigned short f2bu(float v) {
  __hip_bfloat16 b = __float2bfloat16(v);
  return __builtin_bit_cast(unsigned short, b);
}

// ---------------- prep: pack weights ----------------
__global__ __launch_bounds__(256) void prep_kernel(
    const float* __restrict__ wif1, const float* __restrict__ whf1,
    const float* __restrict__ bif1, const float* __restrict__ bhf1,
    const float* __restrict__ wib1, const float* __restrict__ whb1,
    const float* __restrict__ bib1, const float* __restrict__ bhb1,
    const float* __restrict__ wif2, const float* __restrict__ wib2,
    const float* __restrict__ whf2, const float* __restrict__ whb2,
    __hip_bfloat16* __restrict__ WXp, __hip_bfloat16* __restrict__ WHp,
    float* __restrict__ B1, _Float16* __restrict__ W2, float* __restrict__ W2I)
{
  int i = blockIdx.x * 256 + threadIdx.x;
  if (i < PE0) {
    int d = i / 225280; int r = i - d * 225280;
    int p = r / 5120;   int r2 = r - p * 5120;
    int n = r2 >> 3;    int j = r2 & 7;
    int k = p * 8 + j;
    const float* w = d ? wib1 : wif1;
    float v = (n < GG && k < DD) ? w[n * DD + k] : 0.f;
    WXp[i] = __float2bfloat16(v);
  } else if (i < PE1) {
    int ii = i - PE0;
    int d = ii / 102400; int r = ii - d * 102400;
    int p = r / 5120;    int r2 = r - p * 5120;
    int n = r2 >> 3;     int j = r2 & 7;
    int k = p * 8 + j;
    const float* w = d ? whb1 : whf1;
    float v = (n < GG && k < HH) ? w[n * HH + k] : 0.f;
    WHp[ii] = __float2bfloat16(v);
  } else if (i < PE2) {
    int ii = i - PE1;
    int d = ii / NP; int n = ii - d * NP;
    float v = 0.f;
    if (n < GG) v = d ? (bib1[n] + bhb1[n]) : (bif1[n] + bhf1[n]);
    B1[ii] = v;
  } else if (i < PE3) {
    int ii = i - PE2;
    int d = ii / 91200; int r = ii - d * 91200;
    int n = r / 152;    int k = r - n * 152;
    const float* w = d ? whb2 : whf2;
    float v = (k < HH) ? w[n * HH + k] : 0.f;
    W2[ii] = (_Float16)v;
  } else if (i < PE4) {
    int ii = i - PE3;
    int d = ii / 182400; int r = ii - d * 182400;
    int k = r / 608;     int n = r - k * 608;
    const float* w = d ? wib2 : wif2;
    float v = (n < GG) ? w[n * 300 + k] : 0.f;
    W2I[ii] = v;
  }
}

// ---------------- x -> bf16 padded [S][T][352] ----------------
__global__ __launch_bounds__(256) void xcvt_kernel(
    const float* __restrict__ x, __hip_bfloat16* __restrict__ XBF)
{
  const int total4 = NS * TLEN * (KX / 4);   // 11,534,336
  for (int idx = blockIdx.x * 256 + threadIdx.x; idx < total4; idx += gridDim.x * 256) {
    int row = idx / 88;
    int c4 = (idx - row * 88) * 4;
    const float* src = x + (size_t)row * DD + c4;
    float v0 = 0.f, v1 = 0.f, v2 = 0.f, v3 = 0.f;
    if (c4 + 3 < DD) {
      v0 = __builtin_nontemporal_load(src);
      v1 = __builtin_nontemporal_load(src + 1);
      v2 = __builtin_nontemporal_load(src + 2);
      v3 = __builtin_nontemporal_load(src + 3);
    } else {
      if (c4 < DD)     v0 = src[0];
      if (c4 + 1 < DD) v1 = src[1];
      if (c4 + 2 < DD) v2 = src[2];
    }
    u16x4 o;
    o.x = f2bu(v0); o.y = f2bu(v1); o.z = f2bu(v2); o.w = f2bu(v3);
    u16x4* dst = (u16x4*)((unsigned short*)XBF + (size_t)row * KX + c4);
    __builtin_nontemporal_store(o, dst);
  }
}

// ---------------- layer-1 ----------------
// 256 blocks = 128 groups(8 sents) x 2 dirs, 512 threads (8 waves).
// Wave wv owns gate cols [80wv,80wv+80). TB=8 steps = 4 MFMA-row pairs:
// rows 0-7 = step 2p (8 sents), rows 8-15 = step 2p+1. W_hh pinned in 100 VGPRs.
#define XS_SZ   45056u                     // bf16 [4][16][352]
#define HS_OFF  (2u * XS_SZ)               // bf16 [16][160] = 5120
#define GS_OFF  (HS_OFF + 5120u)           // f32  [8][604]  = 19328
#define CF_OFF  (GS_OFF + 19328u)          // f32  [8][152]  = 4864
#define MX_OFF  (CF_OFF + 4864u)           // f32  [8][152]  = 4864
#define L1_SMEM (MX_OFF + 4864u)           // 124288

template<bool BF>
__device__ __forceinline__ void stage_x(char* xsd, const float* __restrict__ x,
                                        const __hip_bfloat16* __restrict__ XBF,
                                        int t0, int dir, int s0, int tid, int lane, int wv)
{
  if constexpr (BF) {
    #pragma unroll
    for (int i = 0; i < 6; ++i) {
      int id = i * 8 + wv;
      if (id < 44) {
        int chunk = id * 64 + lane;
        int row16 = chunk / 44;
        int col16 = chunk - row16 * 44;
        int p = row16 >> 4, rr = row16 & 15;
        int t = t0 + 2 * p + (rr >> 3);
        int s = s0 + (rr & 7);
        int tt = dir ? (127 - t) : t;
        const __hip_bfloat16* gp = XBF + ((size_t)s * TLEN + tt) * KX + col16 * 8;
        gload_lds16((const void*)gp, (void*)(xsd + id * 1024));
      }
    }
  } else {
    for (int e = tid; e < 4 * 16 * KX; e += 512) {
      int row16 = e / KX;
      int col = e - row16 * KX;
      int p = row16 >> 4, rr = row16 & 15;
      int t = t0 + 2 * p + (rr >> 3);
      int s = s0 + (rr & 7);
      int tt = dir ? (127 - t) : t;
      float v = (col < DD) ? x[((size_t)s * TLEN + tt) * DD + col] : 0.f;
      ((__hip_bfloat16*)xsd)[e] = __float2bfloat16(v);
    }
  }
}

__device__ __forceinline__ void cell_pass(float* gs, float* cf, float* mx,
                                          __hip_bfloat16* hs, int tid, bool odd)
{
  for (int e = tid; e < 8 * HH; e += 512) {
    int s = e / HH, j = e - s * HH;
    float iv = sigm(gs[s * 604 + j]);
    float fv = sigm(gs[s * 604 + 150 + j]);
    float gv = tanh_fast(gs[s * 604 + 300 + j]);
    float ov = sigm(gs[s * 604 + 450 + j]);
    float c = fv * cf[s * 152 + j] + iv * gv;
    cf[s * 152 + j] = c;
    float h = ov * tanh_fast(c);
    mx[s * 152 + j] = fmaxf(mx[s * 152 + j], h);
    if (odd) {
      hs[s * 160 + j] = __float2bfloat16(h);
      hs[(8 + s) * 160 + j] = __float2bfloat16(0.f);
    } else {
      hs[(8 + s) * 160 + j] = __float2bfloat16(h);
    }
  }
}

template<bool BF>
__global__ __launch_bounds__(512, 2) void lstm1_kernel(
    const float* __restrict__ x, const __hip_bfloat16* __restrict__ XBF,
    const __hip_bfloat16* __restrict__ WXp, const __hip_bfloat16* __restrict__ WHp,
    const float* __restrict__ B1, float* __restrict__ SE)
{
  extern __shared__ char smem[];
  char* xs0 = smem;
  char* xs1 = smem + XS_SZ;
  __hip_bfloat16* hs = (__hip_bfloat16*)(smem + HS_OFF);
  float* gs = (float*)(smem + GS_OFF);
  float* cf = (float*)(smem + CF_OFF);
  float* mx = (float*)(smem + MX_OFF);

  const int tid = threadIdx.x;
  const int lane = tid & 63;
  const int wv = tid >> 6;
  const int dir = blockIdx.x & 1;
  const int s0 = (blockIdx.x >> 1) * 8;
  const int arow = lane & 15;
  const int kgrp = lane >> 4;
  const int nb = wv * 80;

  for (int e = tid; e < 16 * 160; e += 512) hs[e] = __float2bfloat16(0.f);
  for (int e = tid; e < 8 * 152; e += 512) { cf[e] = 0.f; mx[e] = -3e38f; }

  float bias[5];
  #pragma unroll
  for (int nt = 0; nt < 5; ++nt) {
    int n = nb + nt * 16 + arow;
    bias[nt] = (n < GG) ? B1[dir * NP + n] : 0.f;
    asm volatile("" : "+v"(bias[nt]));
  }

  const __hip_bfloat16* WXd = WXp + (size_t)dir * KXP * NP * 8;
  const __hip_bfloat16* WHd = WHp + (size_t)dir * KHP * NP * 8;

  bf16x8 whr[5][5];
  #pragma unroll
  for (int kh = 0; kh < 5; ++kh)
    #pragma unroll
    for (int nt = 0; nt < 5; ++nt)
      whr[kh][nt] = *reinterpret_cast<const bf16x8*>(
          WHd + ((size_t)(kh * 4 + kgrp) * NP + nb + nt * 16 + arow) * 8);
  // pin W_hh fragments in VGPRs
  #pragma unroll
  for (int kh = 0; kh < 5; ++kh)
    #pragma unroll
    for (int nt = 0; nt < 5; ++nt)
      asm volatile("" : "+v"(whr[kh][nt]));

  stage_x<BF>(xs0, x, XBF, 0, dir, s0, tid, lane, wv);
  bar_full();

  for (int g = 0; g < 16; ++g) {
    char* xsc = (g & 1) ? xs1 : xs0;
    char* xsn = (g & 1) ? xs0 : xs1;
    const __hip_bfloat16* xsb = (const __hip_bfloat16*)xsc;

    f32x4 acc[4][5];
    #pragma unroll
    for (int p = 0; p < 4; ++p)
      #pragma unroll
      for (int nt = 0; nt < 5; ++nt) acc[p][nt] = (f32x4){0.f, 0.f, 0.f, 0.f};

    // ---- phase A: x-projection, 8 steps folded into 4 row-paired tiles ----
    for (int kk = 0; kk < 11; ++kk) {
      bf16x8 a[4], b[5];
      #pragma unroll
      for (int p = 0; p < 4; ++p)
        a[p] = *reinterpret_cast<const bf16x8*>(xsb + (p * 16 + arow) * KX + kk * 32 + kgrp * 8);
      #pragma unroll
      for (int nt = 0; nt < 5; ++nt)
        b[nt] = *reinterpret_cast<const bf16x8*>(
            WXd + ((size_t)(kk * 4 + kgrp) * NP + nb + nt * 16 + arow) * 8);
      #pragma unroll
      for (int p = 0; p < 4; ++p)
        #pragma unroll
        for (int nt = 0; nt < 5; ++nt)
          acc[p][nt] = MFMA_B16(a[p], b[nt], acc[p][nt]);
    }

    // prefetch next g's x while phase B runs (lands by next bar_full)
    if (g < 15)
      stage_x<BF>(xsn, x, XBF, (g + 1) * 8, dir, s0, tid, lane, wv);

    // ---- phase B: 4 pairs = 8 recurrent steps ----
    #pragma unroll
    for (int p = 0; p < 4; ++p) {
      // MFMA1: rows0-7 += h_{2p-1}*Wh (rows8-15 see zeros)
      #pragma unroll
      for (int kh = 0; kh < 5; ++kh) {
        bf16x8 ah = *reinterpret_cast<const bf16x8*>(hs + arow * 160 + kh * 32 + kgrp * 8);
        #pragma unroll
        for (int nt = 0; nt < 5; ++nt)
          acc[p][nt] = MFMA_B16(ah, whr[kh][nt], acc[p][nt]);
      }
      if (kgrp < 2) {
        #pragma unroll
        for (int nt = 0; nt < 5; ++nt) {
          int n = nb + nt * 16 + arow;
          if (n < GG) {
            #pragma unroll
            for (int r = 0; r < 4; ++r)
              gs[(kgrp * 4 + r) * 604 + n] = acc[p][nt][r] + bias[nt];
          }
        }
      }
      bar_lds();
      cell_pass(gs, cf, mx, hs, tid, false);   // h_{2p} -> hs rows 8-15
      bar_lds();
      // MFMA2: rows8-15 += h_{2p}*Wh (rows0-7 get dead garbage)
      #pragma unroll
      for (int kh = 0; kh < 5; ++kh) {
        bf16x8 ah = *reinterpret_cast<const bf16x8*>(hs + arow * 160 + kh * 32 + kgrp * 8);
        #pragma unroll
        for (int nt = 0; nt < 5; ++nt)
          acc[p][nt] = MFMA_B16(ah, whr[kh][nt], acc[p][nt]);
      }
      if (kgrp >= 2) {
        #pragma unroll
        for (int nt = 0; nt < 5; ++nt) {
          int n = nb + nt * 16 + arow;
          if (n < GG) {
            #pragma unroll
            for (int r = 0; r < 4; ++r)
              gs[((kgrp - 2) * 4 + r) * 604 + n] = acc[p][nt][r] + bias[nt];
          }
        }
      }
      bar_lds();
      cell_pass(gs, cf, mx, hs, tid, true);    // h_{2p+1} -> hs rows 0-7, zero rows 8-15
      if (p == 3) bar_full(); else bar_lds();
    }
  }

  for (int e = tid; e < 8 * HH; e += 512) {
    int s = e / HH, j = e - s * HH;
    SE[(size_t)(s0 + s) * 300 + dir * HH + j] = mx[s * 152 + j];
  }
}

// ---------------- layer-2 input projection ----------------
__global__ __launch_bounds__(256, 1) void xg2_kernel(
    const float* __restrict__ SE, const float* __restrict__ W2I,
    const float* __restrict__ bif2, const float* __restrict__ bhf2,
    const float* __restrict__ bib2, const float* __restrict__ bhb2,
    float* __restrict__ XG2)
{
  __shared__ float se[32 * 304];
  const int d = blockIdx.x >> 5, st = blockIdx.x & 31, sb = st * 32;
  const int tid = threadIdx.x;
  for (int e = tid; e < 32 * 300; e += 256) {
    int si = e / 300, k = e - si * 300;
    se[si * 304 + k] = SE[(size_t)(sb + si) * 300 + k];
  }
  __syncthreads();
  for (int pass = 0; pass < 3; ++pass) {
    int n = pass * 256 + tid;
    if (n < GG) {
      float bias = d ? (bib2[n] + bhb2[n]) : (bif2[n] + bhf2[n]);
      float acc[32];
      #pragma unroll
      for (int si = 0; si < 32; ++si) acc[si] = bias;
      const float* wcol = W2I + (size_t)d * 300 * 608 + n;
      for (int k = 0; k < 300; ++k) {
        float wvv = wcol[(size_t)k * 608];
        #pragma unroll
        for (int si = 0; si < 32; ++si) acc[si] += wvv * se[si * 304 + k];
      }
      #pragma unroll
      for (int si = 0; si < 32; ++si)
        XG2[((size_t)d * NS + sb + si) * GG + n] = acc[si];
    }
  }
}

// ---------------- layer-2 recurrence: weights in NAMED VGPR vectors ----------------
__global__ __launch_bounds__(640, 1) void lstm2_kernel(
    const _Float16* __restrict__ W2, const float* __restrict__ XG2,
    float* __restrict__ H2O)
{
  const int dir = blockIdx.x;
  const int t = threadIdx.x;
  const int tr = (t < GG) ? t : (GG - 1);   // clamped row: no divergence below
  __shared__ float gls[640];
  __shared__ __align__(16) uint32 hp[80];

  const u32x4v* wr4 = (const u32x4v*)(W2 + ((size_t)dir * GG + tr) * 152);
  u32x4v w0  = wr4[0],  w1  = wr4[1],  w2  = wr4[2],  w3  = wr4[3];
  u32x4v w4  = wr4[4],  w5  = wr4[5],  w6  = wr4[6],  w7  = wr4[7];
  u32x4v w8  = wr4[8],  w9  = wr4[9],  w10 = wr4[10], w11 = wr4[11];
  u32x4v w12 = wr4[12], w13 = wr4[13], w14 = wr4[14], w15 = wr4[15];
  u32x4v w16 = wr4[16], w17 = wr4[17], w18 = wr4[18];
  asm volatile("" : "+v"(w0), "+v"(w1), "+v"(w2), "+v"(w3), "+v"(w4));
  asm volatile("" : "+v"(w5), "+v"(w6), "+v"(w7), "+v"(w8), "+v"(w9));
  asm volatile("" : "+v"(w10), "+v"(w11), "+v"(w12), "+v"(w13), "+v"(w14));
  asm volatile("" : "+v"(w15), "+v"(w16), "+v"(w17), "+v"(w18));

  if (t < 80) hp[t] = 0u;
  __syncthreads();

  float creg = 0.f;
  const float* xg = XG2 + (size_t)dir * NS * GG;
  const bool isg = (t >= 300) && (t < 450);
  float xnext = xg[(size_t)(dir ? 1023 : 0) * GG + tr];

  for (int step = 0; step < 1024; ++step) {
    const int ss = dir ? (1023 - step) : step;
    float xn = 0.f;
    if (step < 1023) {
      int ss2 = dir ? (1022 - step) : (step + 1);
      xn = xg[(size_t)ss2 * GG + tr];
    }
    const u32x4v* hp4 = reinterpret_cast<const u32x4v*>(hp);
    float a0 = xnext, a1 = 0.f, a2 = 0.f, a3 = 0.f;
#define DOT(i) { u32x4v hv = hp4[i]; \
    a0 = fdot2u(hv.x, w##i.x, a0); a1 = fdot2u(hv.y, w##i.y, a1); \
    a2 = fdot2u(hv.z, w##i.z, a2); a3 = fdot2u(hv.w, w##i.w, a3); }
    DOT(0) DOT(1) DOT(2) DOT(3) DOT(4) DOT(5) DOT(6) DOT(7) DOT(8) DOT(9)
    DOT(10) DOT(11) DOT(12) DOT(13) DOT(14) DOT(15) DOT(16) DOT(17) DOT(18)
#undef DOT
    float acc = (a0 + a1) + (a2 + a3);
    gls[t] = isg ? tanh_fast(acc) : sigm(acc);
    bar_lds();
    if (t < HH) {
      float iv = gls[t], fv = gls[150 + t], gv = gls[300 + t], ov = gls[450 + t];
      creg = fv * creg + iv * gv;
      float nh = ov * tanh_fast(creg);
      H2O[(size_t)ss * 300 + dir * HH + t] = nh;
      ((ushort*)hp)[t] = __half_as_ushort(__float2half(nh));
    }
    bar_lds();
    xnext = xn;
  }
}

// ---------------- head ----------------
__global__ __launch_bounds__(256, 1) void head_kernel(
    const float* __restrict__ H2O, const float* __restrict__ w_out,
    const float* __restrict__ b_out, float* __restrict__ out)
{
  int s = blockIdx.x * 256 + threadIdx.x;
  if (s >= NS) return;
  float acc[7];
  #pragma unroll
  for (int c = 0; c < 7; ++c) acc[c] = b_out[c];
  const float* hrow = H2O + (size_t)s * 300;
  for (int k = 0; k < 300; ++k) {
    float hv = hrow[k];
    #pragma unroll
    for (int c = 0; c < 7; ++c) acc[c] += hv * w_out[c * 300 + k];
  }
  float m = acc[0];
  #pragma unroll
  for (int c = 1; c < 7; ++c) m = fmaxf(m, acc[c]);
  float sum = 0.f;
  #pragma unroll
  for (int c = 0; c < 7; ++c) sum += __expf(acc[c] - m);
  float lse = m + __logf(sum);
  #pragma unroll
  for (int c = 0; c < 7; ++c) out[s * 7 + c] = acc[c] - lse;
}

extern "C" void kernel_launch(void* const* d_in, const int* in_sizes, int n_in,
                              void* d_out, int out_size, void* d_ws, size_t ws_size,
                              hipStream_t stream) {
  const float* x      = (const float*)d_in[0];
  const float* wif1   = (const float*)d_in[1];
  const float* whf1   = (const float*)d_in[2];
  const float* bif1   = (const float*)d_in[3];
  const float* bhf1   = (const float*)d_in[4];
  const float* wib1   = (const float*)d_in[5];
  const float* whb1   = (const float*)d_in[6];
  const float* bib1   = (const float*)d_in[7];
  const float* bhb1   = (const float*)d_in[8];
  const float* wif2   = (const float*)d_in[9];
  const float* whf2   = (const float*)d_in[10];
  const float* bif2   = (const float*)d_in[11];
  const float* bhf2   = (const float*)d_in[12];
  const float* wib2   = (const float*)d_in[13];
  const float* whb2   = (const float*)d_in[14];
  const float* bib2   = (const float*)d_in[15];
  const float* bhb2   = (const float*)d_in[16];
  const float* w_out  = (const float*)d_in[17];
  const float* b_out  = (const float*)d_in[18];

  char* ws = (char*)d_ws;
  __hip_bfloat16* WXp = (__hip_bfloat16*)(ws + OFF_WXP);
  __hip_bfloat16* WHp = (__hip_bfloat16*)(ws + OFF_WHP);
  float*    B1  = (float*)(ws + OFF_B1);
  _Float16* W2  = (_Float16*)(ws + OFF_W2);
  float*    W2I = (float*)(ws + OFF_W2I);
  float*    SE  = (float*)(ws + OFF_SE);
  float*    XG2 = (float*)(ws + OFF_XG2);
  float*    H2O = (float*)(ws + OFF_H2O);
  __hip_bfloat16* XBF = (__hip_bfloat16*)(ws + OFF_XBF);

  const bool useBF = (ws_size >= NEED_BF);

  prep_kernel<<<(PE4 + 255) / 256, 256, 0, stream>>>(
      wif1, whf1, bif1, bhf1, wib1, whb1, bib1, bhb1,
      wif2, wib2, whf2, whb2, WXp, WHp, B1, W2, W2I);

  if (useBF)
    xcvt_kernel<<<4096, 256, 0, stream>>>(x, XBF);

  (void)hipFuncSetAttribute((const void*)(lstm1_kernel<true>),
                            hipFuncAttributeMaxDynamicSharedMemorySize, L1_SMEM);
  (void)hipFuncSetAttribute((const void*)(lstm1_kernel<false>),
                            hipFuncAttributeMaxDynamicSharedMemorySize, L1_SMEM);

  if (useBF)
    lstm1_kernel<true><<<256, 512, L1_SMEM, stream>>>(x, XBF, WXp, WHp, B1, SE);
  else
    lstm1_kernel<false><<<256, 512, L1_SMEM, stream>>>(x, XBF, WXp, WHp, B1, SE);

  xg2_kernel<<<64, 256, 0, stream>>>(SE, W2I, bif2, bhf2, bib2, bhb2, XG2);

  lstm2_kernel<<<2, 640, 0, stream>>>(W2, XG2, H2O);

  head_kernel<<<4, 256, 0, stream>>>(H2O, w_out, b_out, (float*)d_out);
}